// Round 4
// baseline (140.521 us; speedup 1.0000x reference)
//
#include <hip/hip_runtime.h>
#include <hip/hip_bf16.h>
#include <math.h>

// Fused ConvTranspose2d(64->64,k4,s2,p1) + BN + softmax(C) + maxpool2x2 via bf16 MFMA.
//
// R11: R10 post-mortem fixes (R10: 47us, conflicts 6.16M = ~10us DS waste,
// FETCH 51MB from 3x halo redundancy, 1-deep weight prefetch ~150cy work vs
// ~225cy L2 latency per ks):
//  - 2 pooled rows per block (1024 blocks x 512 thr, 4 halo rows = 2x
//    redundancy); each wave: 1 class x 2 rows -> 16 MFMA per ks (2x prefetch
//    cover).
//  - red[2][64][65] f32, pitch 65 (65 == 1 mod 32 -> cout spreads banks);
//    cross-class maxpool via ds_max_u32 on float bits (v >= 0, order-
//    preserving; native, no CAS risk). Was: pitch-64 XOR swizzle -> 8-way
//    conflicts on every ds_max_f32.
//  - LDS 32768(xs) + 33280(red) = 66048 -> 2 blocks/CU; launch_bounds(512,4)
//    keeps combined VGPR+AGPR <= 128 (acc 64 + bf 32 + af/addr ~30).

typedef __attribute__((ext_vector_type(8))) short short8;
typedef __attribute__((ext_vector_type(4))) float floatx4;
typedef __attribute__((ext_vector_type(2))) unsigned uint2v;
typedef __attribute__((ext_vector_type(4))) unsigned uint4v;

__device__ ushort g_wfrag[4 * 8 * 4 * 64 * 8];  // [class][ks][nt][lane][j], 128 KB
__device__ float g_aff[64];  // ((bias-mean)*A + beta) * log2e

#define L2E 1.44269504088896340736f

__device__ __forceinline__ ushort f2bf(float f) {
  union { float f; unsigned u; } v; v.f = f;
  unsigned r = v.u + 0x7FFF + ((v.u >> 16) & 1);  // RNE
  return (ushort)(r >> 16);
}

// prep: thread = (cin pair, cout). BN scale A and log2(e) folded into weights.
__global__ __launch_bounds__(256) void prep_kernel(
    const float* __restrict__ w, const float* __restrict__ bias,
    const float* __restrict__ gamma, const float* __restrict__ beta,
    const float* __restrict__ mean, const float* __restrict__ var) {
  int t = blockIdx.x * 256 + threadIdx.x;  // 0..2047
  int cin0 = (t >> 6) * 2;                 // even cin
  int cout = t & 63;
  int nt = cout >> 4, b15 = cout & 15;
  int q = (cin0 & 31) >> 3;                // quad within k-step
  int j = cin0 & 7;                        // j within quad (even)
  int ksq = cin0 >> 5;                     // which 32-block within tap
  float Aw = gamma[cout] * rsqrtf(var[cout] + 1e-5f) * L2E;

  const float4* p0 = (const float4*)&w[(cin0 * 64 + cout) * 16];
  const float4* p1 = (const float4*)&w[((cin0 + 1) * 64 + cout) * 16];
  float a[16], b[16];
  {
    float4 f0 = p0[0], f1 = p0[1], f2 = p0[2], f3 = p0[3];
    a[0]=f0.x; a[1]=f0.y; a[2]=f0.z; a[3]=f0.w; a[4]=f1.x; a[5]=f1.y; a[6]=f1.z; a[7]=f1.w;
    a[8]=f2.x; a[9]=f2.y; a[10]=f2.z; a[11]=f2.w; a[12]=f3.x; a[13]=f3.y; a[14]=f3.z; a[15]=f3.w;
    float4 g0 = p1[0], g1 = p1[1], g2 = p1[2], g3 = p1[3];
    b[0]=g0.x; b[1]=g0.y; b[2]=g0.z; b[3]=g0.w; b[4]=g1.x; b[5]=g1.y; b[6]=g1.z; b[7]=g1.w;
    b[8]=g2.x; b[9]=g2.y; b[10]=g2.z; b[11]=g2.w; b[12]=g3.x; b[13]=g3.y; b[14]=g3.z; b[15]=g3.w;
  }
#pragma unroll
  for (int kh = 0; kh < 4; ++kh)
#pragma unroll
    for (int kw = 0; kw < 4; ++kw) {
      int r = (kh & 1) ? 0 : 1;
      int pp = (kw & 1) ? 0 : 1;
      int c = r * 2 + pp;
      int tap = (kh >> 1) * 2 + (kw >> 1);
      int ks = tap * 2 + ksq;
      unsigned u = (unsigned)f2bf(a[kh * 4 + kw] * Aw) |
                   ((unsigned)f2bf(b[kh * 4 + kw] * Aw) << 16);
      *(unsigned*)&g_wfrag[(((c * 8 + ks) * 4 + nt) * 64 + q * 16 + b15) * 8 + j] = u;
    }

  if (t < 64) {
    float A0 = gamma[t] * rsqrtf(var[t] + 1e-5f);
    g_aff[t] = ((bias[t] - mean[t]) * A0 + beta[t]) * L2E;
  }
}

__device__ __forceinline__ unsigned cvtpk(float a, float b) {
  unsigned r;
  asm("v_cvt_pk_bf16_f32 %0, %1, %2" : "=v"(r) : "v"(a), "v"(b));
  return r;
}

__device__ __forceinline__ short8 and8(short8 v, unsigned m) {
  union { short8 s; uint4v u; } x;
  x.s = v;
  x.u &= m;
  return x.s;
}

template <int CTRL>
__device__ __forceinline__ float dpp_add(float v) {
  unsigned t = (unsigned)__builtin_amdgcn_update_dpp(
      0, (int)__float_as_uint(v), CTRL, 0xF, 0xF, true);
  return v + __uint_as_float(t);
}

// sum across each 16-lane group (lanes differing in bits 0..3), result in all
// lanes, pure-VALU via DPP: quad_perm xor1, xor2, row_half_mirror, row_mirror.
__device__ __forceinline__ float sum16(float v) {
  v = dpp_add<0xB1>(v);   // quad_perm [1,0,3,2]  (xor 1)
  v = dpp_add<0x4E>(v);   // quad_perm [2,3,0,1]  (xor 2)
  v = dpp_add<0x141>(v);  // row_half_mirror      (xor 4)
  v = dpp_add<0x140>(v);  // row_mirror           (xor 8)
  return v;
}

__device__ __forceinline__ float fexp2(float x) {
#if __has_builtin(__builtin_amdgcn_exp2f)
  return __builtin_amdgcn_exp2f(x);
#else
  return exp2f(x);
#endif
}

__global__ __launch_bounds__(512, 4) void fused_kernel(const float* __restrict__ x,
                                                       float* __restrict__ out) {
  __shared__ __align__(16) ushort xs[4 * 64 * 64];  // 32768 B halo, swizzled
  __shared__ __align__(16) float red[2 * 64 * 65];  // 33280 B pooled-max, pitch 65

  const int tid  = threadIdx.x;
  const int ph0  = blockIdx.x * 2;  // first pooled row
  const int n    = blockIdx.y;
  const int wave = tid >> 6;
  const int lane = tid & 63;
  const int b15  = lane & 15;
  const int q    = lane >> 4;
  const int wc   = wave & 1;   // col half (32 cols)
  const int c    = wave >> 1;  // parity class (r,p)
  const int r    = c >> 1, p = c & 1;

  // ---- zero the pooled-max buffer (covered by the staging barrier) ----
  {
    float4 z = {0.f, 0.f, 0.f, 0.f};
    for (int e = tid; e < 2080; e += 512) ((float4*)red)[e] = z;
  }

  // ---- stage x halo rows ph0-1..ph0+2, 64 cin bf16, swizzled [row][col][chunk^(col&7)] ----
  for (int e = tid; e < 1024; e += 512) {
    int iw4 = e & 15;          // group of 4 iw
    int c4  = (e >> 4) & 15;   // group of 4 cin
    int row = e >> 8;          // 0..3
    int ih  = ph0 - 1 + row;
    float4 v0 = {0.f, 0.f, 0.f, 0.f}, v1 = v0, v2 = v0, v3 = v0;
    if (ih >= 0 && ih < 64) {
      const float* xp = x + ((n * 64 + c4 * 4) * 64 + ih) * 64 + iw4 * 4;
      v0 = *(const float4*)xp;          v1 = *(const float4*)(xp + 4096);
      v2 = *(const float4*)(xp + 8192); v3 = *(const float4*)(xp + 12288);
    }
    int chunk = c4 >> 1, half4 = (c4 & 1) * 4;
    float cc[4][4] = {{v0.x, v1.x, v2.x, v3.x}, {v0.y, v1.y, v2.y, v3.y},
                      {v0.z, v1.z, v2.z, v3.z}, {v0.w, v1.w, v2.w, v3.w}};
#pragma unroll
    for (int ii = 0; ii < 4; ++ii) {
      int col = iw4 * 4 + ii;
      uint2v pk = {cvtpk(cc[ii][0], cc[ii][1]), cvtpk(cc[ii][2], cc[ii][3])};
      *(uint2v*)&xs[(row * 64 + col) * 64 + ((chunk ^ (col & 7)) * 8) + half4] = pk;
    }
  }

  // BN bias (already * log2e) -> MFMA C-in
  float Dc[4];
#pragma unroll
  for (int nt = 0; nt < 4; ++nt) Dc[nt] = g_aff[nt * 16 + b15];

  // edge masks: b==0 steps have dx=p (af1 OOB iff p==1,wc==1,b15==15);
  //             b==1 steps have dx=p-1 (af0 OOB iff p==0,wc==0,b15==0)
  const unsigned m_b0 = (p == 1 && wc == 1 && b15 == 15) ? 0u : ~0u;
  const unsigned m_b1 = (p == 0 && wc == 0 && b15 == 0) ? 0u : ~0u;

  // a-frag LDS base addresses (ushort idx), [mt][b][par]; prow/a add row strides
  int A_[2][2][2];
#pragma unroll
  for (int mt = 0; mt < 2; ++mt)
#pragma unroll
    for (int b = 0; b < 2; ++b) {
      int col = (wc * 32 + mt * 16 + b15 + (b ? p - 1 : p)) & 63;
#pragma unroll
      for (int par = 0; par < 2; ++par)
        A_[mt][b][par] = r * 4096 + col * 64 + (((par * 4 + q) ^ (col & 7)) * 8);
    }

  // first b-frag load issued before the barrier (independent of LDS)
  short8 bfA[4], bfB[4];
  {
    const short8* wf = (const short8*)g_wfrag + (c * 8) * 256;
#pragma unroll
    for (int nt = 0; nt < 4; ++nt) bfA[nt] = wf[nt * 64 + lane];
  }
  __syncthreads();

  floatx4 acc[16];  // [prow][mt][nt], C-in = BN bias
#pragma unroll
  for (int i = 0; i < 16; ++i) {
    float d = Dc[i & 3];
    acc[i] = (floatx4){d, d, d, d};
  }

#pragma unroll
  for (int ks = 0; ks < 8; ++ks) {
    const int a = ks >> 2, b = (ks >> 1) & 1, par = ks & 1;
    short8* cur = (ks & 1) ? bfB : bfA;
    short8* nxt = (ks & 1) ? bfA : bfB;
    if (ks < 7) {  // prefetch next ks's weights (in flight across 16 MFMAs)
      const short8* wf = (const short8*)g_wfrag + (c * 8 + ks + 1) * 256;
#pragma unroll
      for (int nt = 0; nt < 4; ++nt) nxt[nt] = wf[nt * 64 + lane];
    }
    const int hb = a ? 0 : 4096;  // hrow = prow + r + (a?0:1)
#pragma unroll
    for (int prow = 0; prow < 2; ++prow) {
      short8 a0 = *(const short8*)&xs[A_[0][b][par] + prow * 4096 + hb];
      short8 a1 = *(const short8*)&xs[A_[1][b][par] + prow * 4096 + hb];
      if (b == 0) a1 = and8(a1, m_b0);
      else        a0 = and8(a0, m_b1);
#pragma unroll
      for (int nt = 0; nt < 4; ++nt) {
        acc[prow * 8 + nt] =
            __builtin_amdgcn_mfma_f32_16x16x32_bf16(a0, cur[nt], acc[prow * 8 + nt], 0, 0, 0);
        acc[prow * 8 + 4 + nt] =
            __builtin_amdgcn_mfma_f32_16x16x32_bf16(a1, cur[nt], acc[prow * 8 + 4 + nt], 0, 0, 0);
      }
    }
  }

  // ---- softmax (exp2 of pre-scaled logits) + cross-class maxpool via ds_max_u32 ----
  // (softmax outputs >= 0 -> float bit pattern is order-preserving as unsigned)
#pragma unroll
  for (int prow = 0; prow < 2; ++prow)
#pragma unroll
    for (int mt = 0; mt < 2; ++mt) {
      float sm[4] = {0.f, 0.f, 0.f, 0.f};
#pragma unroll
      for (int nt = 0; nt < 4; ++nt)
#pragma unroll
        for (int reg = 0; reg < 4; ++reg) {
          float e = fexp2(acc[prow * 8 + mt * 4 + nt][reg]);
          acc[prow * 8 + mt * 4 + nt][reg] = e;
          sm[reg] += e;
        }
#pragma unroll
      for (int reg = 0; reg < 4; ++reg)
        sm[reg] = __builtin_amdgcn_rcpf(sum16(sm[reg]));
#pragma unroll
      for (int nt = 0; nt < 4; ++nt) {
        int idx = (prow * 64 + nt * 16 + b15) * 65 + wc * 32 + mt * 16 + q * 4;
#pragma unroll
        for (int reg = 0; reg < 4; ++reg) {
          float v = acc[prow * 8 + mt * 4 + nt][reg] * sm[reg];
          __hip_atomic_fetch_max((unsigned*)&red[idx + reg], __float_as_uint(v),
                                 __ATOMIC_RELAXED, __HIP_MEMORY_SCOPE_WORKGROUP);
        }
      }
    }
  __syncthreads();

  // ---- coalesced float4 stores ----
  for (int e = tid; e < 2048; e += 512) {
    int pw4  = e & 15;
    int cout = (e >> 4) & 63;
    int rl   = e >> 10;
    int base = (rl * 64 + cout) * 65 + pw4 * 4;
    float4 v = {red[base], red[base + 1], red[base + 2], red[base + 3]};
    *(float4*)&out[((n * 64 + cout) * 64 + (ph0 + rl)) * 64 + pw4 * 4] = v;
  }
}

extern "C" void kernel_launch(void* const* d_in, const int* in_sizes, int n_in,
                              void* d_out, int out_size, void* d_ws, size_t ws_size,
                              hipStream_t stream) {
  const float* x     = (const float*)d_in[0];
  const float* w     = (const float*)d_in[1];
  const float* bias  = (const float*)d_in[2];
  const float* gamma = (const float*)d_in[3];
  const float* beta  = (const float*)d_in[4];
  const float* mean  = (const float*)d_in[5];
  const float* var   = (const float*)d_in[6];
  float* out = (float*)d_out;

  prep_kernel<<<8, 256, 0, stream>>>(w, bias, gamma, beta, mean, var);
  dim3 grid(32, 32);  // (2-row groups, n)
  fused_kernel<<<grid, 512, 0, stream>>>(x, out);
}

// Round 6
// 115.380 us; speedup vs baseline: 1.2179x; 1.2179x over previous
//
#include <hip/hip_runtime.h>
#include <hip/hip_bf16.h>
#include <math.h>

// Fused ConvTranspose2d(64->64,k4,s2,p1) + BN + softmax(C) + maxpool2x2 via bf16 MFMA.
//
// R13 == R12 resubmit (R12 bench died to a container/infra failure, no counters).
// R12: surgical repair of R10 (R11's 2-prow variant spilled: 64 AGPR acc +
// launch_bounds(512,4) 128-reg cap -> 87MB scratch writes, 62us).
// Back to R10 structure (1 pooled row/block, 512 thr, class-per-wave,
// VGPR ~40), with the two counter-diagnosed fixes:
//  - red[64][65] f32, pitch 65 (== 1 mod 32 -> cout spreads banks; per-atomic
//    max 4-way, avg ~2-way vs R10's 8-way XOR layout, which cost 6.16M
//    conflict-cycles ~= 10us of DS time). Atomic = ds_max_u32 on float bits
//    (softmax outputs > 0 -> unsigned order == float order).
//  - XCD-grouping swizzle ph = (bx&7)*8 + (bx>>3): consecutive pooled rows
//    (sharing 2/3 halo rows) land on the same XCD L2 -> FETCH 51 -> ~38MB.
//  - LDS 24576(xs) + 16704(red) = 41280 -> up to 3 blocks/CU at
//    launch_bounds(512,6).

typedef __attribute__((ext_vector_type(8))) short short8;
typedef __attribute__((ext_vector_type(4))) float floatx4;
typedef __attribute__((ext_vector_type(2))) unsigned uint2v;
typedef __attribute__((ext_vector_type(4))) unsigned uint4v;

__device__ ushort g_wfrag[4 * 8 * 4 * 64 * 8];  // [class][ks][nt][lane][j], 128 KB
__device__ float g_aff[64];  // ((bias-mean)*A + beta) * log2e

#define L2E 1.44269504088896340736f

__device__ __forceinline__ ushort f2bf(float f) {
  union { float f; unsigned u; } v; v.f = f;
  unsigned r = v.u + 0x7FFF + ((v.u >> 16) & 1);  // RNE
  return (ushort)(r >> 16);
}

// prep: thread = (cin pair, cout). BN scale A and log2(e) folded into weights.
__global__ __launch_bounds__(256) void prep_kernel(
    const float* __restrict__ w, const float* __restrict__ bias,
    const float* __restrict__ gamma, const float* __restrict__ beta,
    const float* __restrict__ mean, const float* __restrict__ var) {
  int t = blockIdx.x * 256 + threadIdx.x;  // 0..2047
  int cin0 = (t >> 6) * 2;                 // even cin
  int cout = t & 63;
  int nt = cout >> 4, b15 = cout & 15;
  int q = (cin0 & 31) >> 3;                // quad within k-step
  int j = cin0 & 7;                        // j within quad (even)
  int ksq = cin0 >> 5;                     // which 32-block within tap
  float Aw = gamma[cout] * rsqrtf(var[cout] + 1e-5f) * L2E;

  const float4* p0 = (const float4*)&w[(cin0 * 64 + cout) * 16];
  const float4* p1 = (const float4*)&w[((cin0 + 1) * 64 + cout) * 16];
  float a[16], b[16];
  {
    float4 f0 = p0[0], f1 = p0[1], f2 = p0[2], f3 = p0[3];
    a[0]=f0.x; a[1]=f0.y; a[2]=f0.z; a[3]=f0.w; a[4]=f1.x; a[5]=f1.y; a[6]=f1.z; a[7]=f1.w;
    a[8]=f2.x; a[9]=f2.y; a[10]=f2.z; a[11]=f2.w; a[12]=f3.x; a[13]=f3.y; a[14]=f3.z; a[15]=f3.w;
    float4 g0 = p1[0], g1 = p1[1], g2 = p1[2], g3 = p1[3];
    b[0]=g0.x; b[1]=g0.y; b[2]=g0.z; b[3]=g0.w; b[4]=g1.x; b[5]=g1.y; b[6]=g1.z; b[7]=g1.w;
    b[8]=g2.x; b[9]=g2.y; b[10]=g2.z; b[11]=g2.w; b[12]=g3.x; b[13]=g3.y; b[14]=g3.z; b[15]=g3.w;
  }
#pragma unroll
  for (int kh = 0; kh < 4; ++kh)
#pragma unroll
    for (int kw = 0; kw < 4; ++kw) {
      int r = (kh & 1) ? 0 : 1;
      int pp = (kw & 1) ? 0 : 1;
      int c = r * 2 + pp;
      int tap = (kh >> 1) * 2 + (kw >> 1);
      int ks = tap * 2 + ksq;
      unsigned u = (unsigned)f2bf(a[kh * 4 + kw] * Aw) |
                   ((unsigned)f2bf(b[kh * 4 + kw] * Aw) << 16);
      *(unsigned*)&g_wfrag[(((c * 8 + ks) * 4 + nt) * 64 + q * 16 + b15) * 8 + j] = u;
    }

  if (t < 64) {
    float A0 = gamma[t] * rsqrtf(var[t] + 1e-5f);
    g_aff[t] = ((bias[t] - mean[t]) * A0 + beta[t]) * L2E;
  }
}

__device__ __forceinline__ unsigned cvtpk(float a, float b) {
  unsigned r;
  asm("v_cvt_pk_bf16_f32 %0, %1, %2" : "=v"(r) : "v"(a), "v"(b));
  return r;
}

__device__ __forceinline__ short8 and8(short8 v, unsigned m) {
  union { short8 s; uint4v u; } x;
  x.s = v;
  x.u &= m;
  return x.s;
}

template <int CTRL>
__device__ __forceinline__ float dpp_add(float v) {
  unsigned t = (unsigned)__builtin_amdgcn_update_dpp(
      0, (int)__float_as_uint(v), CTRL, 0xF, 0xF, true);
  return v + __uint_as_float(t);
}

// sum across each 16-lane group (lanes differing in bits 0..3), result in all
// lanes, pure-VALU via DPP: quad_perm xor1, xor2, row_half_mirror, row_mirror.
__device__ __forceinline__ float sum16(float v) {
  v = dpp_add<0xB1>(v);   // quad_perm [1,0,3,2]  (xor 1)
  v = dpp_add<0x4E>(v);   // quad_perm [2,3,0,1]  (xor 2)
  v = dpp_add<0x141>(v);  // row_half_mirror      (xor 4)
  v = dpp_add<0x140>(v);  // row_mirror           (xor 8)
  return v;
}

__device__ __forceinline__ float fexp2(float x) {
#if __has_builtin(__builtin_amdgcn_exp2f)
  return __builtin_amdgcn_exp2f(x);
#else
  return exp2f(x);
#endif
}

__global__ __launch_bounds__(512, 6) void fused_kernel(const float* __restrict__ x,
                                                       float* __restrict__ out) {
  __shared__ __align__(16) ushort xs[3 * 64 * 64];   // 24576 B halo, swizzled
  __shared__ __align__(16) float red[64 * 65 + 16];  // 16704 B pooled-max, pitch 65

  const int tid  = threadIdx.x;
  // XCD-grouping: consecutive ph (sharing 2/3 halo rows) -> same XCD L2
  const int ph   = ((blockIdx.x & 7) << 3) | (blockIdx.x >> 3);  // bijective on [0,64)
  const int n    = blockIdx.y;
  const int wave = tid >> 6;
  const int lane = tid & 63;
  const int b15  = lane & 15;
  const int q    = lane >> 4;
  const int wc   = wave & 1;   // col half (32 cols)
  const int c    = wave >> 1;  // parity class (r,p)
  const int r    = c >> 1, p = c & 1;

  // ---- zero the pooled-max buffer (covered by the staging barrier) ----
  {
    float4 z = {0.f, 0.f, 0.f, 0.f};
    for (int e = tid; e < 1044; e += 512) ((float4*)red)[e] = z;
  }

  // ---- stage x halo rows ph-1..ph+1, 64 cin bf16, swizzled [row][col][chunk^(col&7)] ----
  for (int e = tid; e < 768; e += 512) {
    int iw4 = e & 15;          // group of 4 iw
    int c4  = (e >> 4) & 15;   // group of 4 cin
    int row = e >> 8;          // 0..2
    int ih  = ph - 1 + row;
    float4 v0 = {0.f, 0.f, 0.f, 0.f}, v1 = v0, v2 = v0, v3 = v0;
    if (ih >= 0 && ih < 64) {
      const float* xp = x + ((n * 64 + c4 * 4) * 64 + ih) * 64 + iw4 * 4;
      v0 = *(const float4*)xp;          v1 = *(const float4*)(xp + 4096);
      v2 = *(const float4*)(xp + 8192); v3 = *(const float4*)(xp + 12288);
    }
    int chunk = c4 >> 1, half4 = (c4 & 1) * 4;
    float cc[4][4] = {{v0.x, v1.x, v2.x, v3.x}, {v0.y, v1.y, v2.y, v3.y},
                      {v0.z, v1.z, v2.z, v3.z}, {v0.w, v1.w, v2.w, v3.w}};
#pragma unroll
    for (int ii = 0; ii < 4; ++ii) {
      int col = iw4 * 4 + ii;
      uint2v pk = {cvtpk(cc[ii][0], cc[ii][1]), cvtpk(cc[ii][2], cc[ii][3])};
      *(uint2v*)&xs[(row * 64 + col) * 64 + ((chunk ^ (col & 7)) * 8) + half4] = pk;
    }
  }

  // BN bias (already * log2e) -> MFMA C-in
  float Dc[4];
#pragma unroll
  for (int nt = 0; nt < 4; ++nt) Dc[nt] = g_aff[nt * 16 + b15];

  // edge masks: b==0 steps have dx=p (af1 OOB iff p==1,wc==1,b15==15);
  //             b==1 steps have dx=p-1 (af0 OOB iff p==0,wc==0,b15==0)
  const unsigned m_b0 = (p == 1 && wc == 1 && b15 == 15) ? 0u : ~0u;
  const unsigned m_b1 = (p == 0 && wc == 0 && b15 == 0) ? 0u : ~0u;

  // a-frag LDS addresses (ushort idx), [mt][b][par]; hrow folds into imm offset
  int A_[2][2][2];
#pragma unroll
  for (int mt = 0; mt < 2; ++mt)
#pragma unroll
    for (int b = 0; b < 2; ++b) {
      int col = (wc * 32 + mt * 16 + b15 + (b ? p - 1 : p)) & 63;
#pragma unroll
      for (int par = 0; par < 2; ++par)
        A_[mt][b][par] = r * 4096 + col * 64 + (((par * 4 + q) ^ (col & 7)) * 8);
    }

  // first b-frag load issued before the barrier (independent of LDS)
  short8 bfA[4], bfB[4];
  {
    const short8* wf = (const short8*)g_wfrag + (c * 8) * 256;
#pragma unroll
    for (int nt = 0; nt < 4; ++nt) bfA[nt] = wf[nt * 64 + lane];
  }
  __syncthreads();

  floatx4 acc[8];  // [mt*4+nt], C-in = BN bias
#pragma unroll
  for (int nt = 0; nt < 4; ++nt) {
    acc[nt]     = (floatx4){Dc[nt], Dc[nt], Dc[nt], Dc[nt]};
    acc[4 + nt] = (floatx4){Dc[nt], Dc[nt], Dc[nt], Dc[nt]};
  }

#pragma unroll
  for (int ks = 0; ks < 8; ++ks) {
    const int a = ks >> 2, b = (ks >> 1) & 1, par = ks & 1;
    short8* cur = (ks & 1) ? bfB : bfA;
    short8* nxt = (ks & 1) ? bfA : bfB;
    if (ks < 7) {  // prefetch next ks's weights (in flight across the MFMAs)
      const short8* wf = (const short8*)g_wfrag + (c * 8 + ks + 1) * 256;
#pragma unroll
      for (int nt = 0; nt < 4; ++nt) nxt[nt] = wf[nt * 64 + lane];
    }
    const int ho = a ? 0 : 4096;  // hrow = r + (a?0:1), r folded into A_
    short8 af0 = *(const short8*)&xs[A_[0][b][par] + ho];
    short8 af1 = *(const short8*)&xs[A_[1][b][par] + ho];
    if (b == 0) af1 = and8(af1, m_b0);
    else        af0 = and8(af0, m_b1);
#pragma unroll
    for (int nt = 0; nt < 4; ++nt) {
      acc[nt]     = __builtin_amdgcn_mfma_f32_16x16x32_bf16(af0, cur[nt], acc[nt], 0, 0, 0);
      acc[4 + nt] = __builtin_amdgcn_mfma_f32_16x16x32_bf16(af1, cur[nt], acc[4 + nt], 0, 0, 0);
    }
  }

  // ---- softmax (exp2 of pre-scaled logits) + cross-class maxpool via ds_max_u32 ----
  // (softmax outputs > 0 -> float bit pattern is order-preserving as unsigned)
#pragma unroll
  for (int mt = 0; mt < 2; ++mt) {
    float sm[4] = {0.f, 0.f, 0.f, 0.f};
#pragma unroll
    for (int nt = 0; nt < 4; ++nt)
#pragma unroll
      for (int reg = 0; reg < 4; ++reg) {
        float e = fexp2(acc[mt * 4 + nt][reg]);
        acc[mt * 4 + nt][reg] = e;
        sm[reg] += e;
      }
#pragma unroll
    for (int reg = 0; reg < 4; ++reg)
      sm[reg] = __builtin_amdgcn_rcpf(sum16(sm[reg]));
#pragma unroll
    for (int nt = 0; nt < 4; ++nt) {
      int idx = (nt * 16 + b15) * 65 + wc * 32 + mt * 16 + q * 4;
#pragma unroll
      for (int reg = 0; reg < 4; ++reg) {
        float v = acc[mt * 4 + nt][reg] * sm[reg];
        __hip_atomic_fetch_max((unsigned*)&red[idx + reg], __float_as_uint(v),
                               __ATOMIC_RELAXED, __HIP_MEMORY_SCOPE_WORKGROUP);
      }
    }
  }
  __syncthreads();

  // ---- coalesced stores (ds_read2_b32 pairs; float2 global) ----
  for (int e = tid; e < 2048; e += 512) {
    int pw2  = e & 31;
    int cout = e >> 5;
    int base = cout * 65 + pw2 * 2;
    float2 val = {red[base], red[base + 1]};
    *(float2*)&out[((n * 64 + cout) * 64 + ph) * 64 + pw2 * 2] = val;
  }
}

extern "C" void kernel_launch(void* const* d_in, const int* in_sizes, int n_in,
                              void* d_out, int out_size, void* d_ws, size_t ws_size,
                              hipStream_t stream) {
  const float* x     = (const float*)d_in[0];
  const float* w     = (const float*)d_in[1];
  const float* bias  = (const float*)d_in[2];
  const float* gamma = (const float*)d_in[3];
  const float* beta  = (const float*)d_in[4];
  const float* mean  = (const float*)d_in[5];
  const float* var   = (const float*)d_in[6];
  float* out = (float*)d_out;

  prep_kernel<<<8, 256, 0, stream>>>(w, bias, gamma, beta, mean, var);
  dim3 grid(64, 32);  // (pooled row [XCD-swizzled], n)
  fused_kernel<<<grid, 512, 0, stream>>>(x, out);
}